// Round 6
// baseline (493.172 us; speedup 1.0000x reference)
//
#include <hip/hip_runtime.h>

#define DIN 2048
#define DOUT 2048
#define NHEADS 16
#define HDIM 128
#define LATENT 256
#define BB 2
#define SS 2048
#define MTOT (BB*SS)
#define QLD (DOUT + LATENT)   // fused q|latent row stride = 2304
#define KLD (2*DOUT)          // fused k|v row stride = 4096

using bf16 = __bf16;
using bf16x8 = __attribute__((ext_vector_type(8))) __bf16;
using f32x4 = __attribute__((ext_vector_type(4))) float;

__device__ __forceinline__ void gload16(const bf16* g, bf16* l) {
    __builtin_amdgcn_global_load_lds(
        (const __attribute__((address_space(1))) void*)g,
        (__attribute__((address_space(3))) void*)l, 16, 0, 0);
}

// ---------------- cast fp32 -> bf16 (vectorized) ----------------
__global__ void cast_f32_bf16(const float* __restrict__ in, bf16* __restrict__ out, int n) {
    int i = (blockIdx.x * blockDim.x + threadIdx.x) * 8;
    if (i >= n) return;
    float4 a = *(const float4*)(in + i);
    float4 b = *(const float4*)(in + i + 4);
    bf16x8 o;
    o[0] = (bf16)a.x; o[1] = (bf16)a.y; o[2] = (bf16)a.z; o[3] = (bf16)a.w;
    o[4] = (bf16)b.x; o[5] = (bf16)b.y; o[6] = (bf16)b.z; o[7] = (bf16)b.w;
    *(bf16x8*)(out + i) = o;
}

// ---------------- transpose + cast: W[R][C] fp32 -> WT[C][R] bf16 ----------------
__global__ void transpose_cast(const float* __restrict__ W, bf16* __restrict__ WT, int R, int C) {
    __shared__ float tile[32][33];
    int c0 = blockIdx.x * 32, r0 = blockIdx.y * 32;
    int tx = threadIdx.x & 31, ty = threadIdx.x >> 5;
    #pragma unroll
    for (int i = ty; i < 32; i += 8)
        tile[i][tx] = W[(size_t)(r0 + i) * C + c0 + tx];
    __syncthreads();
    #pragma unroll
    for (int i = ty; i < 32; i += 8)
        WT[(size_t)(c0 + i) * R + r0 + tx] = (bf16)tile[tx][i];
}

// two same-shape transposes in one launch (z picks the pair)
__global__ void transpose_cast2(const float* __restrict__ W0, bf16* __restrict__ T0,
                                const float* __restrict__ W1, bf16* __restrict__ T1,
                                int R, int C) {
    const float* W = blockIdx.z ? W1 : W0;
    bf16* WT = blockIdx.z ? T1 : T0;
    __shared__ float tile[32][33];
    int c0 = blockIdx.x * 32, r0 = blockIdx.y * 32;
    int tx = threadIdx.x & 31, ty = threadIdx.x >> 5;
    #pragma unroll
    for (int i = ty; i < 32; i += 8)
        tile[i][tx] = W[(size_t)(r0 + i) * C + c0 + tx];
    __syncthreads();
    #pragma unroll
    for (int i = ty; i < 32; i += 8)
        WT[(size_t)(c0 + i) * R + r0 + tx] = (bf16)tile[tx][i];
}

// ---------------- transpose v (cols 2048.. of kvb) -> vT[b][h][d][s] ----------------
__global__ void transpose_v(const bf16* __restrict__ v, bf16* __restrict__ vT) {
    int bh = blockIdx.z;
    int s0 = blockIdx.x * 32, d0 = blockIdx.y * 32;
    __shared__ bf16 t[32][33];
    int tx = threadIdx.x & 31, ty = threadIdx.x >> 5;
    int b = bh >> 4, h = bh & 15;
    #pragma unroll
    for (int i = ty; i < 32; i += 8)
        t[i][tx] = v[(size_t)(b * SS + s0 + i) * KLD + h * HDIM + d0 + tx];
    __syncthreads();
    #pragma unroll
    for (int i = ty; i < 32; i += 8)
        vT[((size_t)bh * HDIM + d0 + i) * SS + s0 + tx] = t[tx][i];
}

// ---------------- GEMM: C[M][*] = A[M][K] @ BT[N][K]^T (+bias) ----------------
// m97 structure; strided A (Ald) and C (Cld) for fused outputs; XCD-swizzled grid.
template<bool OUT_F32, bool BIAS>
__global__ __launch_bounds__(256) void gemm_bt(const bf16* __restrict__ A,
        const bf16* __restrict__ BT, void* __restrict__ Cp,
        const float* __restrict__ bias, const int Kdim, const int Ald,
        const int Ndim, const int Cld) {
    const int nwg = gridDim.x * gridDim.y;
    int orig = blockIdx.y * gridDim.x + blockIdx.x;
    int swz = (orig & 7) * (nwg >> 3) + (orig >> 3);
    const int n0 = (swz % gridDim.x) * 128, m0 = (swz / gridDim.x) * 128;

    const int tid = threadIdx.x, wave = tid >> 6, lane = tid & 63;
    const int wm = wave >> 1, wn = wave & 1;
    const int lr = lane & 15, lg = lane >> 4;
    __shared__ __align__(16) bf16 As[128][32];
    __shared__ __align__(16) bf16 Bs[128][32];
    f32x4 acc[4][4];
    #pragma unroll
    for (int i = 0; i < 4; ++i)
        #pragma unroll
        for (int j = 0; j < 4; ++j) acc[i][j] = (f32x4){0.f, 0.f, 0.f, 0.f};

    const int sr = lane >> 2;
    const int sc = (lane & 3) * 8;
    const bf16* ga = A  + (size_t)(m0 + wave * 16 + sr) * Ald + sc;
    const bf16* gb = BT + (size_t)(n0 + wave * 16 + sr) * Kdim + sc;
    const size_t strideA64 = (size_t)64 * Ald;
    const size_t strideB64 = (size_t)64 * Kdim;
    bf16* lAd = &As[wave * 16][0];
    bf16* lBd = &Bs[wave * 16][0];

    for (int k0 = 0; k0 < Kdim; k0 += 32) {
        gload16(ga,             lAd);
        gload16(ga + strideA64, lAd + 64 * 32);
        gload16(gb,             lBd);
        gload16(gb + strideB64, lBd + 64 * 32);
        ga += 32; gb += 32;
        __syncthreads();
        bf16x8 af[4], bfr[4];
        #pragma unroll
        for (int i = 0; i < 4; ++i)
            af[i] = *(const bf16x8*)&As[wm * 64 + i * 16 + lr][lg * 8];
        #pragma unroll
        for (int j = 0; j < 4; ++j)
            bfr[j] = *(const bf16x8*)&Bs[wn * 64 + j * 16 + lr][lg * 8];
        #pragma unroll
        for (int i = 0; i < 4; ++i)
            #pragma unroll
            for (int j = 0; j < 4; ++j)
                acc[i][j] = __builtin_amdgcn_mfma_f32_16x16x32_bf16(af[i], bfr[j], acc[i][j], 0, 0, 0);
        __syncthreads();
    }
    #pragma unroll
    for (int i = 0; i < 4; ++i)
        #pragma unroll
        for (int j = 0; j < 4; ++j) {
            const int r0 = m0 + wm * 64 + i * 16 + lg * 4;
            const int c = n0 + wn * 64 + j * 16 + lr;
            #pragma unroll
            for (int r2 = 0; r2 < 4; ++r2) {
                float v = acc[i][j][r2];
                if (BIAS) v += bias[c];
                if (OUT_F32) ((float*)Cp)[(size_t)(r0 + r2) * Cld + c] = v;
                else         ((bf16*)Cp)[(size_t)(r0 + r2) * Cld + c] = (bf16)v;
            }
        }
}

// ---------------- causal flash attention ----------------
// grid (16, 32); block does q-tiles bx and 31-bx (33 K-tiles, uniform).
// Single-buffered K/V/P (40KB LDS -> 4 blocks/CU), global_load_lds staging from
// pre-swizzled global addresses, defer-max softmax, deferred l-reduction.
__global__ __launch_bounds__(256, 4) void attn_kernel(const bf16* __restrict__ q,
        const bf16* __restrict__ k, const bf16* __restrict__ vT, bf16* __restrict__ ctx) {
    // XCD swizzle: 64 consecutive swz-ids (4 bh) per XCD -> K/V L2 locality
    int orig = blockIdx.y * 16 + blockIdx.x;
    int swz = (orig & 7) * 64 + (orig >> 3);
    const int bx = swz & 15, bh = swz >> 4;
    const int b = bh >> 4, h = bh & 15;
    const int tid = threadIdx.x, wave = tid >> 6, lane = tid & 63;
    const int lr = lane & 15, lg = lane >> 4;

    __shared__ __align__(16) char KsB[16384];   // [kc][d], byte ^ ((kc&7)<<4)
    __shared__ __align__(16) char VsB[16384];   // [d][kc], byte ^ ((d&7)<<4)
    __shared__ __align__(16) char PsB[8192];    // [qr][kc], byte ^ ((qr&7)<<4)

    // staging: LDS byte X = wave*4096 + c*1024 + lane*16 (linear dest).
    int krow[4], kcolE[4];
    #pragma unroll
    for (int c = 0; c < 4; ++c) {
        krow[c] = wave * 16 + c * 4 + (lane >> 4);
        kcolE[c] = ((((lane & 15) * 16) ^ ((krow[c] & 7) << 4)) >> 1);
    }
    const int vrow0 = wave * 32 + (lane >> 3);
    const int vcolE = ((((lane & 7) * 16) ^ (((lane >> 3) & 7) << 4)) >> 1);

    const bf16* kbaseP = k  + (size_t)b * SS * KLD + h * HDIM;
    const bf16* vbaseP = vT + (size_t)bh * HDIM * SS;

    const float C = 0.12751743f;  // log2(e)/sqrt(128)

    for (int half = 0; half < 2; ++half) {
        const int qt = half ? (31 - bx) : bx;
        const int q0 = qt * 64;

        bf16x8 qf[4];
        const bf16* qbase = q + ((size_t)(b * SS + q0 + wave * 16 + lr)) * QLD + h * HDIM;
        #pragma unroll
        for (int d = 0; d < 4; ++d) qf[d] = *(const bf16x8*)(qbase + d * 32 + lg * 8);

        f32x4 o[8];
        #pragma unroll
        for (int i = 0; i < 8; ++i) o[i] = (f32x4){0.f, 0.f, 0.f, 0.f};
        float m_i[4], lp[4], mC[4];
        #pragma unroll
        for (int r = 0; r < 4; ++r) { m_i[r] = -3.0e38f; lp[r] = 0.f; mC[r] = -3.8e37f; }

        const int nkt = qt + 1;
        for (int kt = 0; kt < nkt; ++kt) {
            const int kbase = kt * 64;
            {   // stage K (64x128) + V^T (128x64) via async DMA, pre-swizzled source
                bf16* dK = (bf16*)(KsB + wave * 4096);
                bf16* dV = (bf16*)(VsB + wave * 4096);
                #pragma unroll
                for (int c = 0; c < 4; ++c) {
                    gload16(kbaseP + (size_t)(kbase + krow[c]) * KLD + kcolE[c], dK + c * 512);
                    gload16(vbaseP + (size_t)(vrow0 + c * 8) * SS + kbase + vcolE, dV + c * 512);
                }
            }
            __syncthreads();   // compiler drains vmcnt before barrier

            // S = Q @ K^T (raw scores)
            f32x4 sacc[4];
            #pragma unroll
            for (int nf = 0; nf < 4; ++nf) sacc[nf] = (f32x4){0.f, 0.f, 0.f, 0.f};
            __builtin_amdgcn_s_setprio(1);
            #pragma unroll
            for (int nf = 0; nf < 4; ++nf)
                #pragma unroll
                for (int d = 0; d < 4; ++d) {
                    int row = nf * 16 + lr;
                    bf16x8 kf = *(const bf16x8*)(KsB + ((row * 256 + d * 64 + lg * 16) ^ ((row & 7) << 4)));
                    sacc[nf] = __builtin_amdgcn_mfma_f32_16x16x32_bf16(qf[d], kf, sacc[nf], 0, 0, 0);
                }
            __builtin_amdgcn_s_setprio(0);

            float sv[4][4];
            const bool maskt = (kbase + 63 > q0);
            #pragma unroll
            for (int nf = 0; nf < 4; ++nf)
                #pragma unroll
                for (int r = 0; r < 4; ++r) {
                    float s = sacc[nf][r];
                    if (maskt) {
                        int qr = q0 + wave * 16 + lg * 4 + r;
                        int kc = kbase + nf * 16 + lr;
                        if (qr < kc) s = -3.0e38f;
                    }
                    sv[nf][r] = s;
                }
            // per-row tile max (16-lane groups)
            float tmax[4];
            #pragma unroll
            for (int r = 0; r < 4; ++r) {
                float v = fmaxf(fmaxf(sv[0][r], sv[1][r]), fmaxf(sv[2][r], sv[3][r]));
                #pragma unroll
                for (int off = 1; off < 16; off <<= 1) v = fmaxf(v, __shfl_xor(v, off));
                tmax[r] = v;
            }
            // defer-max: rescale only when max grows enough that p could exceed 2^8
            bool need = false;
            #pragma unroll
            for (int r = 0; r < 4; ++r) need = need || ((tmax[r] - m_i[r]) * C > 8.0f);
            if (__any(need)) {
                #pragma unroll
                for (int r = 0; r < 4; ++r) {
                    float mnew = fmaxf(m_i[r], tmax[r]);
                    float corr = __builtin_amdgcn_exp2f((m_i[r] - mnew) * C);
                    m_i[r] = mnew; mC[r] = mnew * C;
                    lp[r] *= corr;
                    #pragma unroll
                    for (int df = 0; df < 8; ++df) o[df][r] *= corr;
                }
            }
            // P = exp2(s*C - m*C); per-lane partial l (no per-tile reduce)
            #pragma unroll
            for (int nf = 0; nf < 4; ++nf)
                #pragma unroll
                for (int r = 0; r < 4; ++r) {
                    float p = __builtin_amdgcn_exp2f(fmaf(sv[nf][r], C, -mC[r]));
                    lp[r] += p;
                    int prow = wave * 16 + lg * 4 + r;
                    *(bf16*)(PsB + ((prow * 128 + (nf * 16 + lr) * 2) ^ ((prow & 7) << 4))) = (bf16)p;
                }

            // O += P @ V
            __builtin_amdgcn_s_setprio(1);
            #pragma unroll
            for (int ks = 0; ks < 2; ++ks) {
                int prow = wave * 16 + lr;
                bf16x8 pf = *(const bf16x8*)(PsB + ((prow * 128 + ks * 64 + lg * 16) ^ ((prow & 7) << 4)));
                #pragma unroll
                for (int df = 0; df < 8; ++df) {
                    int vr2 = df * 16 + lr;
                    bf16x8 vf = *(const bf16x8*)(VsB + ((vr2 * 128 + ks * 64 + lg * 16) ^ ((vr2 & 7) << 4)));
                    o[df] = __builtin_amdgcn_mfma_f32_16x16x32_bf16(pf, vf, o[df], 0, 0, 0);
                }
            }
            __builtin_amdgcn_s_setprio(0);
            __syncthreads();   // all waves done reading K/V before next stage
        }

        // deferred l reduction (once per half), then write out
        #pragma unroll
        for (int r = 0; r < 4; ++r) {
            float v = lp[r];
            #pragma unroll
            for (int off = 1; off < 16; off <<= 1) v += __shfl_xor(v, off);
            float inv = 1.0f / v;
            #pragma unroll
            for (int df = 0; df < 8; ++df) {
                int rrow = q0 + wave * 16 + lg * 4 + r;
                int col = h * HDIM + df * 16 + lr;
                ctx[(size_t)(b * SS + rrow) * DOUT + col] = (bf16)(o[df][r] * inv);
            }
        }
    }
}

extern "C" void kernel_launch(void* const* d_in, const int* in_sizes, int n_in,
                              void* d_out, int out_size, void* d_ws, size_t ws_size,
                              hipStream_t stream) {
    const float* x    = (const float*)d_in[0];
    const float* Wq   = (const float*)d_in[1];
    const float* Wdkv = (const float*)d_in[2];
    const float* Wuk  = (const float*)d_in[3];
    const float* Wuv  = (const float*)d_in[4];
    const float* Wout = (const float*)d_in[5];
    const float* bout = (const float*)d_in[6];

    char* ws = (char*)d_ws;
    size_t off = 0;
    auto alloc = [&](size_t bytes) { char* p = ws + off; off = (off + bytes + 255) & ~255ULL; return p; };
    bf16* xb    = (bf16*)alloc((size_t)MTOT * DIN * 2);
    bf16* WqT   = (bf16*)alloc((size_t)DOUT * DIN * 2);     // adjacent:
    bf16* WdkvT = (bf16*)alloc((size_t)LATENT * DIN * 2);   //   WqT||WdkvT = [2304][2048]
    bf16* WukT  = (bf16*)alloc((size_t)DOUT * LATENT * 2);  // adjacent:
    bf16* WuvT  = (bf16*)alloc((size_t)DOUT * LATENT * 2);  //   WukT||WuvT = [4096][256]
    bf16* WoutT = (bf16*)alloc((size_t)DOUT * DOUT * 2);
    bf16* qlat  = (bf16*)alloc((size_t)MTOT * QLD * 2);     // [4096][2304]: q | latent
    bf16* kvb   = (bf16*)alloc((size_t)MTOT * KLD * 2);     // [4096][4096]: k | v
    bf16* vT    = (bf16*)alloc((size_t)BB * NHEADS * HDIM * SS * 2);
    bf16* ctx   = (bf16*)alloc((size_t)MTOT * DOUT * 2);

    cast_f32_bf16<<<(MTOT * DIN) / 8 / 256, 256, 0, stream>>>(x, xb, MTOT * DIN);
    // {Wq, Wout}: both 2048x2048 -> transposed
    transpose_cast2<<<dim3(DOUT / 32, DIN / 32, 2), 256, 0, stream>>>(Wq, WqT, Wout, WoutT, DIN, DOUT);
    // {Wuk, Wuv}: both 256x2048 -> [2048][256]
    transpose_cast2<<<dim3(DOUT / 32, LATENT / 32, 2), 256, 0, stream>>>(Wuk, WukT, Wuv, WuvT, LATENT, DOUT);
    transpose_cast<<<dim3(LATENT / 32, DIN / 32), 256, 0, stream>>>(Wdkv, WdkvT, DIN, LATENT);

    // fused [q | latent] = xb @ [WqT||WdkvT]^T
    gemm_bt<false, false><<<dim3(QLD / 128, MTOT / 128), 256, 0, stream>>>(
        xb, WqT, qlat, nullptr, DIN, DIN, QLD, QLD);
    // fused [k | v] = latent @ [WukT||WuvT]^T
    gemm_bt<false, false><<<dim3(KLD / 128, MTOT / 128), 256, 0, stream>>>(
        qlat + DOUT, WukT, kvb, nullptr, LATENT, QLD, KLD, KLD);

    transpose_v<<<dim3(SS / 32, HDIM / 32, BB * NHEADS), 256, 0, stream>>>(kvb + DOUT, vT);

    attn_kernel<<<dim3(16, BB * NHEADS), 256, 0, stream>>>(qlat, kvb, vT, ctx);

    gemm_bt<true, true><<<dim3(DOUT / 128, MTOT / 128), 256, 0, stream>>>(
        ctx, WoutT, d_out, bout, DOUT, DOUT, DOUT, DOUT);
}